// Round 4
// baseline (31480.276 us; speedup 1.0000x reference)
//
#include <hip/hip_runtime.h>
#include <hip/hip_bf16.h>

typedef unsigned int uint32;
typedef unsigned short ushort16;

#define GBLK 512
#define BT 256
#define NSTEP 128

// bf16 cache element offsets inside ws (after 64KB header)
#define OFF_WQ    0ull
#define OFF_WHH1  1048576ull
#define OFF_WHH2  4194304ull
#define OFF_WIH1  7340032ull
#define OFF_WIH2  15204352ull
#define OFF_WPRE  24641536ull
#define OFF_WOUT  28311552ull
#define OFF_PK    28835840ull
#define OFF_ENC   29097984ull
#define CONV_TOTAL 29622272ull  // elems; bytes=59244544; +65536 header

struct Params {
  const int* inputs;
  const float *h1_in, *h2_in, *embeds, *vatt;
  const void *pk, *enc, *Wq, *Wih1, *Whh1, *Wih2, *Whh2, *Wpre, *Wout;
  const float *bih1, *bhh1, *bih2, *bhh2, *bpre, *bout;
  float* out;
  float* ws;
  int* bar;
  int cw;
};

__device__ __forceinline__ float blo(uint32 u) { return __uint_as_float(u << 16); }
__device__ __forceinline__ float bhi(uint32 u) { return __uint_as_float(u & 0xffff0000u); }
__device__ __forceinline__ uint32 bfr(float f) {  // fp32 -> bf16 bits, RNE
  uint32 u = __float_as_uint(f);
  return (u + 0x7fffu + ((u >> 16) & 1u)) >> 16;
}

__device__ __forceinline__ float wsum(float v) {
#pragma unroll
  for (int o = 32; o; o >>= 1) v += __shfl_xor(v, o, 64);
  return v;
}

// one 512-wide chunk of a row-dot; W elem index = base + lane*8; x = LDS ptr at chunk start
template <bool CW>
__device__ __forceinline__ float rowchunk(const void* W, size_t base, const float* xc, int lane) {
  const float* x = xc + lane * 8;
  float4 x0 = *(const float4*)x, x1 = *(const float4*)(x + 4);
  if constexpr (CW) {
    uint4 w = *(const uint4*)((const ushort16*)W + base + lane * 8);
    return blo(w.x) * x0.x + bhi(w.x) * x0.y + blo(w.y) * x0.z + bhi(w.y) * x0.w +
           blo(w.z) * x1.x + bhi(w.z) * x1.y + blo(w.w) * x1.z + bhi(w.w) * x1.w;
  } else {
    const float* wf = (const float*)W + base + lane * 8;
    float4 w0 = *(const float4*)wf, w1 = *(const float4*)(wf + 4);
    return w0.x * x0.x + w0.y * x0.y + w0.z * x0.z + w0.w * x0.w +
           w1.x * x1.x + w1.y * x1.y + w1.z * x1.z + w1.w * x1.w;
  }
}

template <bool CW, int K>
__device__ __forceinline__ float rowdot(const void* W, size_t rowbase, const float* x, int lane) {
  float s = 0.f;
#pragma unroll
  for (int c = 0; c < K; c += 512) s += rowchunk<CW>(W, rowbase + c, x + c, lane);
  return wsum(s);
}

// two-level monotonic grid barrier: 16 groups x 32 blocks -> root -> release
__device__ __forceinline__ void gbar(int* bar, int k) {
  __threadfence();
  __syncthreads();
  if (threadIdx.x == 0) {
    const int grp = blockIdx.x & 15;
    int v = __hip_atomic_fetch_add(&bar[grp * 16], 1, __ATOMIC_ACQ_REL, __HIP_MEMORY_SCOPE_AGENT);
    if (v == k * 32 - 1) {
      int r = __hip_atomic_fetch_add(&bar[256], 1, __ATOMIC_ACQ_REL, __HIP_MEMORY_SCOPE_AGENT);
      if (r == k * 16 - 1)
        __hip_atomic_store(&bar[320], k, __ATOMIC_RELEASE, __HIP_MEMORY_SCOPE_AGENT);
    }
    while (__hip_atomic_load(&bar[320], __ATOMIC_RELAXED, __HIP_MEMORY_SCOPE_AGENT) < k) {
      __builtin_amdgcn_s_sleep(2);
    }
    (void)__hip_atomic_load(&bar[320], __ATOMIC_ACQUIRE, __HIP_MEMORY_SCOPE_AGENT);
  }
  __syncthreads();
}

__device__ __forceinline__ float sigm(float x) { return 1.f / (1.f + expf(-x)); }
__device__ __forceinline__ float lrelu(float x) { return x >= 0.f ? x : 0.01f * x; }

__device__ __forceinline__ void conv_arr(const float* src, ushort16* dst, int n, int g) {
  for (int i = g * 4; i < n; i += GBLK * BT * 4) {
    float4 v = *(const float4*)(src + i);
    uint2 o;
    o.x = bfr(v.x) | (bfr(v.y) << 16);
    o.y = bfr(v.z) | (bfr(v.w) << 16);
    *(uint2*)(dst + i) = o;
  }
}

template <bool CW>
__device__ void run_decoder(const Params& p, float* sx, float* s_red, float* s_part) {
  const int tid = threadIdx.x;
  const int lane = tid & 63;
  const int wid = tid >> 6;
  const int b = blockIdx.x;
  const int gw = b * 4 + wid;  // 0..2047

  float* h1w = p.ws + 1024;
  float* h2w = p.ws + 2048;
  float* qw = p.ws + 3072;
  float* evw = p.ws + 4096;   // 256
  float* ctxw = p.ws + 4352;  // 2048
  float* o1w = p.ws + 6400;
  float* o2w = p.ws + 7424;
  float* gh1 = p.ws + 8448;   // 3072
  float* gh2 = p.ws + 11520;  // 3072

  ushort16* cb = (ushort16*)((char*)p.ws + 65536);
  const void* Wqc = CW ? (const void*)(cb + OFF_WQ) : p.Wq;
  const void* Whh1c = CW ? (const void*)(cb + OFF_WHH1) : p.Whh1;
  const void* Whh2c = CW ? (const void*)(cb + OFF_WHH2) : p.Whh2;
  const void* Wih1c = CW ? (const void*)(cb + OFF_WIH1) : p.Wih1;
  const void* Wih2c = CW ? (const void*)(cb + OFF_WIH2) : p.Wih2;
  const void* Wprec = CW ? (const void*)(cb + OFF_WPRE) : p.Wpre;
  const void* Woutc = CW ? (const void*)(cb + OFF_WOUT) : p.Wout;
  const void* pkc = CW ? (const void*)(cb + OFF_PK) : p.pk;
  const void* encc = CW ? (const void*)(cb + OFF_ENC) : p.enc;

  float* outs = p.out;            // 128*512
  float* pres = p.out + 65536;    // 128*1024
  float* alph = p.out + 196608;   // 128*256
  float* h1f = p.out + 229376;
  float* h2f = p.out + 230400;

  if constexpr (CW) {
    const int g = b * BT + tid;
    conv_arr((const float*)p.Wq, cb + OFF_WQ, 1048576, g);
    conv_arr((const float*)p.Whh1, cb + OFF_WHH1, 3145728, g);
    conv_arr((const float*)p.Whh2, cb + OFF_WHH2, 3145728, g);
    conv_arr((const float*)p.Wih1, cb + OFF_WIH1, 7864320, g);
    conv_arr((const float*)p.Wih2, cb + OFF_WIH2, 9437184, g);
    conv_arr((const float*)p.Wpre, cb + OFF_WPRE, 3670016, g);
    conv_arr((const float*)p.Wout, cb + OFF_WOUT, 524288, g);
    conv_arr((const float*)p.pk, cb + OFF_PK, 262144, g);
    conv_arr((const float*)p.enc, cb + OFF_ENC, 524288, g);
  }
  // init recurrent state (f32)
  if (gw < 16) h1w[gw * 64 + lane] = p.h1_in[gw * 64 + lane];
  else if (gw < 32) h2w[(gw - 16) * 64 + lane] = p.h2_in[(gw - 16) * 64 + lane];

  int bk = 0;
  gbar(p.bar, ++bk);

  for (int t = 0; t <= NSTEP; ++t) {
    gbar(p.bar, ++bk);
    // ======== Phase A: epilogue(t-1) [pre,out] + q + gh1 + gh2 ========
    // sx layout: [0:512)=emb(t-1) | [512:1536)=o2 | [1536:3584)=ctx | [3584:4608)=h1 | [4608:5632)=h2
    {
      const float* embp = p.embeds + (size_t)p.inputs[t > 0 ? t - 1 : 0] * 512;
      for (int i2 = tid * 4; i2 < 5632; i2 += BT * 4) {
        float4 v;
        if (i2 < 512) v = *(const float4*)(embp + i2);
        else if (i2 < 1536) v = *(const float4*)(o2w + i2 - 512);
        else if (i2 < 3584) v = *(const float4*)(ctxw + i2 - 1536);
        else if (i2 < 4608) v = *(const float4*)(h1w + i2 - 3584);
        else v = *(const float4*)(h2w + i2 - 4608);
        *(float4*)(sx + i2) = v;
      }
      __syncthreads();
      if (gw < 1024) {
        if (t > 0) {  // pre row gw, x=[emb|o2|ctx] contiguous at sx
          float s = rowdot<CW, 3584>(Wprec, (size_t)gw * 3584, sx, lane);
          if (lane == 0) pres[(size_t)(t - 1) * 1024 + gw] = lrelu(s + p.bpre[gw]);
        }
        for (int j = gw; j < 2048; j += 1024) {  // Whh1 rows 0..2047
          float s = rowdot<CW, 1024>(Whh1c, (size_t)j * 1024, sx + 3584, lane);
          if (lane == 0) gh1[j] = s + p.bhh1[j];
        }
      } else {
        for (int j = 2048 + (gw - 1024); j < 7680; j += 1024) {
          if (j < 3072) {
            float s = rowdot<CW, 1024>(Whh1c, (size_t)j * 1024, sx + 3584, lane);
            if (lane == 0) gh1[j] = s + p.bhh1[j];
          } else if (j < 6144) {
            int r = j - 3072;
            float s = rowdot<CW, 1024>(Whh2c, (size_t)r * 1024, sx + 4608, lane);
            if (lane == 0) gh2[r] = s + p.bhh2[r];
          } else if (j < 7168) {
            int r = j - 6144;
            float s = rowdot<CW, 1024>(Wqc, (size_t)r * 1024, sx + 4608, lane);
            if (lane == 0) qw[r] = s;
          } else if (t > 0) {
            int r = j - 7168;
            float s = rowdot<CW, 1024>(Woutc, (size_t)r * 1024, sx + 512, lane);
            if (lane == 0) outs[(size_t)(t - 1) * 512 + r] = s + p.bout[r];
          }
        }
      }
    }
    if (t == NSTEP) break;

    gbar(p.bar, ++bk);
    // ======== Phase B: e[s] = tanh(pk[s,:]+q)·v, one wave per s (blocks 0..255) ========
    if (b < 256 && wid == 0) {
      const int si = b;
      const int base = lane * 16;
      float pkv[16], qv[16], vv[16];
      if constexpr (CW) {
        const uint4* pp = (const uint4*)((const ushort16*)pkc + (size_t)si * 1024 + base);
        uint4 a = pp[0], c = pp[1];
        pkv[0] = blo(a.x); pkv[1] = bhi(a.x); pkv[2] = blo(a.y); pkv[3] = bhi(a.y);
        pkv[4] = blo(a.z); pkv[5] = bhi(a.z); pkv[6] = blo(a.w); pkv[7] = bhi(a.w);
        pkv[8] = blo(c.x); pkv[9] = bhi(c.x); pkv[10] = blo(c.y); pkv[11] = bhi(c.y);
        pkv[12] = blo(c.z); pkv[13] = bhi(c.z); pkv[14] = blo(c.w); pkv[15] = bhi(c.w);
      } else {
#pragma unroll
        for (int k = 0; k < 4; ++k)
          *(float4*)(pkv + k * 4) = *(const float4*)((const float*)pkc + (size_t)si * 1024 + base + k * 4);
      }
#pragma unroll
      for (int k = 0; k < 4; ++k) {
        *(float4*)(qv + k * 4) = *(const float4*)(qw + base + k * 4);
        *(float4*)(vv + k * 4) = *(const float4*)(p.vatt + base + k * 4);
      }
      float acc = 0.f;
#pragma unroll
      for (int k = 0; k < 16; ++k) acc += tanhf(pkv[k] + qv[k]) * vv[k];
      acc = wsum(acc);
      if (lane == 0) evw[si] = acc;
    }

    gbar(p.bar, ++bk);
    // ======== Phase C: softmax (redundant/block) + 4 context cols/block ========
    {
      float e_i = evw[tid];
      float mw = e_i;
#pragma unroll
      for (int o = 32; o; o >>= 1) mw = fmaxf(mw, __shfl_xor(mw, o, 64));
      if (lane == 0) s_red[wid] = mw;
      __syncthreads();
      float m = fmaxf(fmaxf(s_red[0], s_red[1]), fmaxf(s_red[2], s_red[3]));
      __syncthreads();
      float pe = expf(e_i - m);
      float zw = wsum(pe);
      if (lane == 0) s_red[wid] = zw;
      __syncthreads();
      float Z = s_red[0] + s_red[1] + s_red[2] + s_red[3];
      float alpha = pe / Z;
      if (b == 0) alph[(size_t)t * 256 + tid] = alpha;
      int j0 = b * 4;
      float c0, c1, c2, c3;
      if constexpr (CW) {
        uint2 w = *(const uint2*)((const ushort16*)encc + (size_t)tid * 2048 + j0);
        c0 = blo(w.x); c1 = bhi(w.x); c2 = blo(w.y); c3 = bhi(w.y);
      } else {
        float4 w = *(const float4*)((const float*)encc + (size_t)tid * 2048 + j0);
        c0 = w.x; c1 = w.y; c2 = w.z; c3 = w.w;
      }
      sx[tid * 4 + 0] = alpha * c0;
      sx[tid * 4 + 1] = alpha * c1;
      sx[tid * 4 + 2] = alpha * c2;
      sx[tid * 4 + 3] = alpha * c3;
      __syncthreads();
      for (int st = 128; st >= 1; st >>= 1) {
        if (tid < st) {
#pragma unroll
          for (int j = 0; j < 4; ++j) sx[tid * 4 + j] += sx[(tid + st) * 4 + j];
        }
        __syncthreads();
      }
      if (tid < 4) ctxw[j0 + tid] = sx[tid];
    }

    gbar(p.bar, ++bk);
    // ======== Phase D: GRU1, block owns i0=b*2, i0+1; x=[emb|ctx] (2560) ========
    {
      const float* embc = p.embeds + (size_t)p.inputs[t] * 512;
      for (int i2 = tid * 4; i2 < 2560; i2 += BT * 4) {
        float4 v = (i2 < 512) ? *(const float4*)(embc + i2) : *(const float4*)(ctxw + i2 - 512);
        *(float4*)(sx + i2) = v;
      }
      __syncthreads();
      const int i0 = b * 2;
      for (int mm = wid; mm < 30; mm += 4) {
        int r = mm / 15, m = mm % 15;
        int g = m / 5, c = m % 5;
        int row = g * 1024 + i0 + r;
        float s = rowchunk<CW>(Wih1c, (size_t)row * 2560 + c * 512, sx + c * 512, lane);
        s = wsum(s);
        if (lane == 0) s_part[mm] = s;
      }
      __syncthreads();
      if (tid < 2) {
        const int i = i0 + tid;
        const float* sp = s_part + tid * 15;
        float sr = sp[0] + sp[1] + sp[2] + sp[3] + sp[4];
        float sz = sp[5] + sp[6] + sp[7] + sp[8] + sp[9];
        float sn = sp[10] + sp[11] + sp[12] + sp[13] + sp[14];
        float r = sigm(sr + p.bih1[i] + gh1[i]);
        float z = sigm(sz + p.bih1[1024 + i] + gh1[1024 + i]);
        float n = tanhf(sn + p.bih1[2048 + i] + r * gh1[2048 + i]);
        float h = (1.f - z) * n + z * h1w[i];
        h1w[i] = h;
        o1w[i] = lrelu(h);
      }
    }

    gbar(p.bar, ++bk);
    // ======== Phase E: GRU2, block owns i0=b*2, i0+1; x=[o1|ctx] (3072) ========
    {
      for (int i2 = tid * 4; i2 < 3072; i2 += BT * 4) {
        float4 v = (i2 < 1024) ? *(const float4*)(o1w + i2) : *(const float4*)(ctxw + i2 - 1024);
        *(float4*)(sx + i2) = v;
      }
      __syncthreads();
      const int i0 = b * 2;
      for (int mm = wid; mm < 36; mm += 4) {
        int r = mm / 18, m = mm % 18;
        int g = m / 6, c = m % 6;
        int row = g * 1024 + i0 + r;
        float s = rowchunk<CW>(Wih2c, (size_t)row * 3072 + c * 512, sx + c * 512, lane);
        s = wsum(s);
        if (lane == 0) s_part[mm] = s;
      }
      __syncthreads();
      if (tid < 2) {
        const int i = i0 + tid;
        const float* sp = s_part + tid * 18;
        float sr = sp[0] + sp[1] + sp[2] + sp[3] + sp[4] + sp[5];
        float sz = sp[6] + sp[7] + sp[8] + sp[9] + sp[10] + sp[11];
        float sn = sp[12] + sp[13] + sp[14] + sp[15] + sp[16] + sp[17];
        float r = sigm(sr + p.bih2[i] + gh2[i]);
        float z = sigm(sz + p.bih2[1024 + i] + gh2[1024 + i]);
        float n = tanhf(sn + p.bih2[2048 + i] + r * gh2[2048 + i]);
        float h = (1.f - z) * n + z * h2w[i];
        h2w[i] = h;
        o2w[i] = lrelu(h);
      }
    }
  }
  // ======== Final state outputs ========
  if (gw < 16) h1f[gw * 64 + lane] = h1w[gw * 64 + lane];
  else if (gw < 32) h2f[(gw - 16) * 64 + lane] = h2w[(gw - 16) * 64 + lane];
}

__global__ __launch_bounds__(BT, 2) void dec_SAVE_30683246363209_kernel(Params p) {
  __shared__ float sx[5632];
  __shared__ float s_red[4];
  __shared__ float s_part[40];
  if (p.cw) run_decoder<true>(p, sx, s_red, s_part);
  else run_decoder<false>(p, sx, s_red, s_part);
}

extern "C" void kernel_launch(void* const* d_in, const int* in_sizes, int n_in,
                              void* d_out, int out_size, void* d_ws, size_t ws_size,
                              hipStream_t stream) {
  hipMemsetAsync(d_ws, 0, 65536, stream);  // barriers + cross-block state region

  Params p;
  p.inputs = (const int*)d_in[0];
  p.h1_in = (const float*)d_in[1];
  p.h2_in = (const float*)d_in[2];
  p.pk = d_in[3];
  p.enc = d_in[4];
  p.embeds = (const float*)d_in[5];
  p.Wq = d_in[6];
  p.vatt = (const float*)d_in[7];
  p.Wih1 = d_in[8];
  p.Whh1 = d_in[9];
  p.bih1 = (const float*)d_in[10];
  p.bhh1 = (const float*)d_in[11];
  p.Wih2 = d_in[12];
  p.Whh2 = d_in[13];
  p.bih2 = (const float*)d_in[14];
  p.bhh2 = (const float*)d_in[15];
  p.Wpre = d_in[16];
  p.bpre = (const float*)d_in[17];
  p.Wout = d_in[18];
  p.bout = (const float*)d_in[19];
  p.out = (float*)d_out;
  p.ws = (float*)d_ws;
  p.bar = (int*)d_ws;
  p.cw = (ws_size >= (size_t)(65536 + CONV_TOTAL * 2)) ? 1 : 0;

  void* args[] = {&p};
  hipError_t err = hipLaunchCooperativeKernel((const void*)dec_SAVE_30683246363209_kernel,
                                              dim3(GBLK), dim3(BT), args, 0, stream);
  if (err != hipSuccess) {
    // Fallback: plain launch. Grid (512 blocks, 2/CU by __launch_bounds__) fits
    // co-resident on 256 CUs, so the custom barrier remains safe.
    dec_SAVE_30683246363209_kernel<<<dim3(GBLK), dim3(BT), 0, stream>>>(p);
  }
}

// Round 5
// 6848.455 us; speedup vs baseline: 4.5967x; 4.5967x over previous
//
#include <hip/hip_runtime.h>
#include <hip/hip_bf16.h>

typedef unsigned int uint32;
typedef unsigned short ushort16;

#define GBLK 256
#define BT 512
#define NSTEP 128

// bf16 cache element offsets inside ws (after 64KB header)
#define OFF_WQ    0ull
#define OFF_WHH1  1048576ull
#define OFF_WHH2  4194304ull
#define OFF_WIH1  7340032ull
#define OFF_WIH2  15204352ull
#define OFF_WPRE  24641536ull
#define OFF_WOUT  28311552ull
#define OFF_PK    28835840ull
#define OFF_ENC   29097984ull
#define CONV_TOTAL 29622272ull  // elems; bytes=59244544; +65536 header

struct Params {
  const int* inputs;
  const float *h1_in, *h2_in, *embeds, *vatt;
  const void *pk, *enc, *Wq, *Wih1, *Whh1, *Wih2, *Whh2, *Wpre, *Wout;
  const float *bih1, *bhh1, *bih2, *bhh2, *bpre, *bout;
  float* out;
  float* ws;
  int* bar;
  int cw;
};

__device__ __forceinline__ float blo(uint32 u) { return __uint_as_float(u << 16); }
__device__ __forceinline__ float bhi(uint32 u) { return __uint_as_float(u & 0xffff0000u); }
__device__ __forceinline__ uint32 bfr(float f) {  // fp32 -> bf16 bits, RNE
  uint32 u = __float_as_uint(f);
  return (u + 0x7fffu + ((u >> 16) & 1u)) >> 16;
}

// Agent-scope (MALL-coherent, L2-bypassing) state access. Cross-block state
// flows ONLY through these, so barriers need no acquire -> no buffer_inv ->
// weight lines stay warm in per-XCD L2 across all 128 steps.
__device__ __forceinline__ float ald(const float* a) {
  return __hip_atomic_load(a, __ATOMIC_RELAXED, __HIP_MEMORY_SCOPE_AGENT);
}
__device__ __forceinline__ void ast(float* a, float v) {
  __hip_atomic_store(a, v, __ATOMIC_RELAXED, __HIP_MEMORY_SCOPE_AGENT);
}

__device__ __forceinline__ float wsum(float v) {
#pragma unroll
  for (int o = 32; o; o >>= 1) v += __shfl_xor(v, o, 64);
  return v;
}

// one 512-wide chunk of a row-dot; W elem index = base + lane*8; x = LDS ptr at chunk start
template <bool CW>
__device__ __forceinline__ float rowchunk(const void* W, size_t base, const float* xc, int lane) {
  const float* x = xc + lane * 8;
  float4 x0 = *(const float4*)x, x1 = *(const float4*)(x + 4);
  if constexpr (CW) {
    uint4 w = *(const uint4*)((const ushort16*)W + base + lane * 8);
    return blo(w.x) * x0.x + bhi(w.x) * x0.y + blo(w.y) * x0.z + bhi(w.y) * x0.w +
           blo(w.z) * x1.x + bhi(w.z) * x1.y + blo(w.w) * x1.z + bhi(w.w) * x1.w;
  } else {
    const float* wf = (const float*)W + base + lane * 8;
    float4 w0 = *(const float4*)wf, w1 = *(const float4*)(wf + 4);
    return w0.x * x0.x + w0.y * x0.y + w0.z * x0.z + w0.w * x0.w +
           w1.x * x1.x + w1.y * x1.y + w1.z * x1.z + w1.w * x1.w;
  }
}

template <bool CW, int K>
__device__ __forceinline__ float rowdot(const void* W, size_t rowbase, const float* x, int lane) {
  float s = 0.f;
#pragma unroll
  for (int c = 0; c < K; c += 512) s += rowchunk<CW>(W, rowbase + c, x + c, lane);
  return wsum(s);
}

// Barrier v3: 16 groups x 16 blocks; two-level arrival AND two-level release.
// Spinners per cache line <= 16. RELAXED spins (no L2 invalidate). RELEASE on
// arrival adds (wbl2: flushes dirty output/conv lines; weights are clean).
__device__ __forceinline__ void gbar(int* bar, int k) {
  __syncthreads();
  if (threadIdx.x == 0) {
    const int grp = blockIdx.x >> 4;
    int* gcnt = bar + grp * 32;         // group arrival counter (128B apart)
    int* grel = bar + 512 + grp * 32;   // group release word
    int* rcnt = bar + 1024;             // root arrival counter
    int* rrel = bar + 1056;             // root release word (separate line)
    int v = __hip_atomic_fetch_add(gcnt, 1, __ATOMIC_RELEASE, __HIP_MEMORY_SCOPE_AGENT);
    if (v == k * 16 - 1) {  // last block of this group
      int r = __hip_atomic_fetch_add(rcnt, 1, __ATOMIC_RELEASE, __HIP_MEMORY_SCOPE_AGENT);
      if (r == k * 16 - 1)
        __hip_atomic_store(rrel, k, __ATOMIC_RELAXED, __HIP_MEMORY_SCOPE_AGENT);
      while (__hip_atomic_load(rrel, __ATOMIC_RELAXED, __HIP_MEMORY_SCOPE_AGENT) < k)
        __builtin_amdgcn_s_sleep(1);
      __hip_atomic_store(grel, k, __ATOMIC_RELAXED, __HIP_MEMORY_SCOPE_AGENT);
    } else {
      while (__hip_atomic_load(grel, __ATOMIC_RELAXED, __HIP_MEMORY_SCOPE_AGENT) < k)
        __builtin_amdgcn_s_sleep(1);
    }
  }
  __syncthreads();
}

__device__ __forceinline__ float sigm(float x) { return 1.f / (1.f + expf(-x)); }
__device__ __forceinline__ float lrelu(float x) { return x >= 0.f ? x : 0.01f * x; }

__device__ __forceinline__ void conv_arr(const float* src, ushort16* dst, int n, int g) {
  for (int i = g * 4; i < n; i += GBLK * BT * 4) {
    float4 v = *(const float4*)(src + i);
    uint2 o;
    o.x = bfr(v.x) | (bfr(v.y) << 16);
    o.y = bfr(v.z) | (bfr(v.w) << 16);
    *(uint2*)(dst + i) = o;
  }
}

template <bool CW>
__device__ void run_decoder(const Params& p, float* sx, float* s_red, float* s_part) {
  const int tid = threadIdx.x;
  const int lane = tid & 63;
  const int w = tid >> 6;            // wave 0..7
  const int b = blockIdx.x;
  const int gw = b * 8 + w;          // 0..2047

  // state arrays (all cross-block traffic via ald/ast)
  float* h1w = p.ws + 2048;
  float* h2w = p.ws + 3072;
  float* qw = p.ws + 4096;
  float* evw = p.ws + 5120;   // 256
  float* ctxw = p.ws + 5376;  // 2048
  float* o1w = p.ws + 7424;
  float* o2w = p.ws + 8448;
  float* gh1 = p.ws + 9472;   // 3072
  float* gh2 = p.ws + 12544;  // 3072

  ushort16* cb = (ushort16*)((char*)p.ws + 65536);
  const void* Wqc = CW ? (const void*)(cb + OFF_WQ) : p.Wq;
  const void* Whh1c = CW ? (const void*)(cb + OFF_WHH1) : p.Whh1;
  const void* Whh2c = CW ? (const void*)(cb + OFF_WHH2) : p.Whh2;
  const void* Wih1c = CW ? (const void*)(cb + OFF_WIH1) : p.Wih1;
  const void* Wih2c = CW ? (const void*)(cb + OFF_WIH2) : p.Wih2;
  const void* Wprec = CW ? (const void*)(cb + OFF_WPRE) : p.Wpre;
  const void* Woutc = CW ? (const void*)(cb + OFF_WOUT) : p.Wout;
  const void* pkc = CW ? (const void*)(cb + OFF_PK) : p.pk;
  const void* encc = CW ? (const void*)(cb + OFF_ENC) : p.enc;

  float* outs = p.out;            // 128*512
  float* pres = p.out + 65536;    // 128*1024
  float* alph = p.out + 196608;   // 128*256
  float* h1f = p.out + 229376;
  float* h2f = p.out + 230400;

  if constexpr (CW) {
    const int g = b * BT + tid;
    conv_arr((const float*)p.Wq, cb + OFF_WQ, 1048576, g);
    conv_arr((const float*)p.Whh1, cb + OFF_WHH1, 3145728, g);
    conv_arr((const float*)p.Whh2, cb + OFF_WHH2, 3145728, g);
    conv_arr((const float*)p.Wih1, cb + OFF_WIH1, 7864320, g);
    conv_arr((const float*)p.Wih2, cb + OFF_WIH2, 9437184, g);
    conv_arr((const float*)p.Wpre, cb + OFF_WPRE, 3670016, g);
    conv_arr((const float*)p.Wout, cb + OFF_WOUT, 524288, g);
    conv_arr((const float*)p.pk, cb + OFF_PK, 262144, g);
    conv_arr((const float*)p.enc, cb + OFF_ENC, 524288, g);
  }
  // init recurrent state (agent-scope stores)
  if (gw < 16) ast(h1w + gw * 64 + lane, p.h1_in[gw * 64 + lane]);
  else if (gw < 32) ast(h2w + (gw - 16) * 64 + lane, p.h2_in[(gw - 16) * 64 + lane]);

  int bk = 0;
  gbar(p.bar, ++bk);  // conv stores flushed by RELEASE-wbl2 on arrival

  for (int t = 0; t <= NSTEP; ++t) {
    gbar(p.bar, ++bk);
    // ======== Phase A: epilogue(t-1) [pre,out] + q + gh1 + gh2 ========
    // sx: [0:512)=emb(t-1) | [512:1536)=o2 | [1536:3584)=ctx | [3584:4608)=h1 | [4608:5632)=h2
    {
      const float* embp = p.embeds + (size_t)p.inputs[t > 0 ? t - 1 : 0] * 512;
      for (int i = tid; i < 5632; i += BT) {
        float v;
        if (i < 512) v = embp[i];
        else if (i < 1536) v = ald(o2w + i - 512);
        else if (i < 3584) v = ald(ctxw + i - 1536);
        else if (i < 4608) v = ald(h1w + i - 3584);
        else v = ald(h2w + i - 4608);
        sx[i] = v;
      }
      __syncthreads();
      if (gw < 1024) {
        if (t > 0) {  // pre row gw
          float s = rowdot<CW, 3584>(Wprec, (size_t)gw * 3584, sx, lane);
          if (lane == 0) pres[(size_t)(t - 1) * 1024 + gw] = lrelu(s + p.bpre[gw]);
        }
        for (int j = gw; j < 2048; j += 1024) {  // Whh1 rows 0..2047
          float s = rowdot<CW, 1024>(Whh1c, (size_t)j * 1024, sx + 3584, lane);
          if (lane == 0) ast(gh1 + j, s + p.bhh1[j]);
        }
      } else {
        for (int j = 2048 + (gw - 1024); j < 7680; j += 1024) {
          if (j < 3072) {
            float s = rowdot<CW, 1024>(Whh1c, (size_t)j * 1024, sx + 3584, lane);
            if (lane == 0) ast(gh1 + j, s + p.bhh1[j]);
          } else if (j < 6144) {
            int r = j - 3072;
            float s = rowdot<CW, 1024>(Whh2c, (size_t)r * 1024, sx + 4608, lane);
            if (lane == 0) ast(gh2 + r, s + p.bhh2[r]);
          } else if (j < 7168) {
            int r = j - 6144;
            float s = rowdot<CW, 1024>(Wqc, (size_t)r * 1024, sx + 4608, lane);
            if (lane == 0) ast(qw + r, s);
          } else if (t > 0) {
            int r = j - 7168;
            float s = rowdot<CW, 1024>(Woutc, (size_t)r * 1024, sx + 512, lane);
            if (lane == 0) outs[(size_t)(t - 1) * 512 + r] = s + p.bout[r];
          }
        }
      }
    }
    if (t == NSTEP) break;

    gbar(p.bar, ++bk);
    // ======== Phase B: e[b] = tanh(pk[b,:]+q)·v, wave 0 of each block ========
    if (w == 0) {
      const int base = lane * 16;
      float pkv[16], qv[16], vv[16];
      if constexpr (CW) {
        const uint4* pp = (const uint4*)((const ushort16*)pkc + (size_t)b * 1024 + base);
        uint4 a = pp[0], c = pp[1];
        pkv[0] = blo(a.x); pkv[1] = bhi(a.x); pkv[2] = blo(a.y); pkv[3] = bhi(a.y);
        pkv[4] = blo(a.z); pkv[5] = bhi(a.z); pkv[6] = blo(a.w); pkv[7] = bhi(a.w);
        pkv[8] = blo(c.x); pkv[9] = bhi(c.x); pkv[10] = blo(c.y); pkv[11] = bhi(c.y);
        pkv[12] = blo(c.z); pkv[13] = bhi(c.z); pkv[14] = blo(c.w); pkv[15] = bhi(c.w);
      } else {
#pragma unroll
        for (int k = 0; k < 4; ++k)
          *(float4*)(pkv + k * 4) = *(const float4*)((const float*)pkc + (size_t)b * 1024 + base + k * 4);
      }
#pragma unroll
      for (int k = 0; k < 16; ++k) qv[k] = ald(qw + base + k);
#pragma unroll
      for (int k = 0; k < 4; ++k)
        *(float4*)(vv + k * 4) = *(const float4*)(p.vatt + base + k * 4);
      float acc = 0.f;
#pragma unroll
      for (int k = 0; k < 16; ++k) acc += tanhf(pkv[k] + qv[k]) * vv[k];
      acc = wsum(acc);
      if (lane == 0) ast(evw + b, acc);
    }

    gbar(p.bar, ++bk);
    // ======== Phase C: softmax (redundant/block, tid<256) + 8 ctx cols/block ========
    {
      float e_i = 0.f, pe = 0.f;
      if (tid < 256) {
        e_i = ald(evw + tid);
        float mw = e_i;
#pragma unroll
        for (int o = 32; o; o >>= 1) mw = fmaxf(mw, __shfl_xor(mw, o, 64));
        if (lane == 0) s_red[w] = mw;
      }
      __syncthreads();
      float m = fmaxf(fmaxf(s_red[0], s_red[1]), fmaxf(s_red[2], s_red[3]));
      __syncthreads();
      if (tid < 256) {
        pe = expf(e_i - m);
        float zw = wsum(pe);
        if (lane == 0) s_red[w] = zw;
      }
      __syncthreads();
      float Z = s_red[0] + s_red[1] + s_red[2] + s_red[3];
      const int j0 = b * 8;
      if (tid < 256) {
        float alpha = pe / Z;
        if (b == 0) alph[(size_t)t * 256 + tid] = alpha;
        float c[8];
        if constexpr (CW) {
          uint4 wv = *(const uint4*)((const ushort16*)encc + (size_t)tid * 2048 + j0);
          c[0] = blo(wv.x); c[1] = bhi(wv.x); c[2] = blo(wv.y); c[3] = bhi(wv.y);
          c[4] = blo(wv.z); c[5] = bhi(wv.z); c[6] = blo(wv.w); c[7] = bhi(wv.w);
        } else {
          const float* er = (const float*)encc + (size_t)tid * 2048 + j0;
          *(float4*)c = *(const float4*)er;
          *(float4*)(c + 4) = *(const float4*)(er + 4);
        }
#pragma unroll
        for (int j = 0; j < 8; ++j) sx[tid * 8 + j] = alpha * c[j];
      }
      __syncthreads();
      for (int st = 128; st >= 1; st >>= 1) {
        if (tid < st) {
#pragma unroll
          for (int j = 0; j < 8; ++j) sx[tid * 8 + j] += sx[(tid + st) * 8 + j];
        }
        __syncthreads();
      }
      if (tid < 8) ast(ctxw + j0 + tid, sx[tid]);
    }

    gbar(p.bar, ++bk);
    // ======== Phase D: GRU1, block owns i0..i0+3; x=[emb|ctx] (2560) ========
    {
      const float* embc = p.embeds + (size_t)p.inputs[t] * 512;
      for (int i = tid; i < 2560; i += BT)
        sx[i] = (i < 512) ? embc[i] : ald(ctxw + i - 512);
      __syncthreads();
      const int i0 = b * 4;
      for (int mm = w; mm < 60; mm += 8) {
        int r = mm / 15, m = mm % 15;
        int g = m / 5, c = m % 5;
        int row = g * 1024 + i0 + r;
        float s = rowchunk<CW>(Wih1c, (size_t)row * 2560 + c * 512, sx + c * 512, lane);
        s = wsum(s);
        if (lane == 0) s_part[mm] = s;
      }
      __syncthreads();
      if (tid < 4) {
        const int i = i0 + tid;
        const float* sp = s_part + tid * 15;
        float sr = sp[0] + sp[1] + sp[2] + sp[3] + sp[4];
        float sz = sp[5] + sp[6] + sp[7] + sp[8] + sp[9];
        float sn = sp[10] + sp[11] + sp[12] + sp[13] + sp[14];
        float r = sigm(sr + p.bih1[i] + ald(gh1 + i));
        float z = sigm(sz + p.bih1[1024 + i] + ald(gh1 + 1024 + i));
        float n = tanhf(sn + p.bih1[2048 + i] + r * ald(gh1 + 2048 + i));
        float h = (1.f - z) * n + z * ald(h1w + i);
        ast(h1w + i, h);
        ast(o1w + i, lrelu(h));
      }
    }

    gbar(p.bar, ++bk);
    // ======== Phase E: GRU2, block owns i0..i0+3; x=[o1|ctx] (3072) ========
    {
      for (int i = tid; i < 3072; i += BT)
        sx[i] = (i < 1024) ? ald(o1w + i) : ald(ctxw + i - 1024);
      __syncthreads();
      const int i0 = b * 4;
      for (int mm = w; mm < 72; mm += 8) {
        int r = mm / 18, m = mm % 18;
        int g = m / 6, c = m % 6;
        int row = g * 1024 + i0 + r;
        float s = rowchunk<CW>(Wih2c, (size_t)row * 3072 + c * 512, sx + c * 512, lane);
        s = wsum(s);
        if (lane == 0) s_part[mm] = s;
      }
      __syncthreads();
      if (tid < 4) {
        const int i = i0 + tid;
        const float* sp = s_part + tid * 18;
        float sr = sp[0] + sp[1] + sp[2] + sp[3] + sp[4] + sp[5];
        float sz = sp[6] + sp[7] + sp[8] + sp[9] + sp[10] + sp[11];
        float sn = sp[12] + sp[13] + sp[14] + sp[15] + sp[16] + sp[17];
        float r = sigm(sr + p.bih2[i] + ald(gh2 + i));
        float z = sigm(sz + p.bih2[1024 + i] + ald(gh2 + 1024 + i));
        float n = tanhf(sn + p.bih2[2048 + i] + r * ald(gh2 + 2048 + i));
        float h = (1.f - z) * n + z * ald(h2w + i);
        ast(h2w + i, h);
        ast(o2w + i, lrelu(h));
      }
    }
  }
  // ======== Final state outputs ========
  if (gw < 16) h1f[gw * 64 + lane] = ald(h1w + gw * 64 + lane);
  else if (gw < 32) h2f[(gw - 16) * 64 + lane] = ald(h2w + (gw - 16) * 64 + lane);
}

__global__ __launch_bounds__(BT, 2) void dec_SAVE_30683246363209_kernel(Params p) {
  __shared__ float sx[5632];
  __shared__ float s_red[8];
  __shared__ float s_part[72];
  if (p.cw) run_decoder<true>(p, sx, s_red, s_part);
  else run_decoder<false>(p, sx, s_red, s_part);
}

extern "C" void kernel_launch(void* const* d_in, const int* in_sizes, int n_in,
                              void* d_out, int out_size, void* d_ws, size_t ws_size,
                              hipStream_t stream) {
  hipMemsetAsync(d_ws, 0, 65536, stream);  // barrier lines + state region

  Params p;
  p.inputs = (const int*)d_in[0];
  p.h1_in = (const float*)d_in[1];
  p.h2_in = (const float*)d_in[2];
  p.pk = d_in[3];
  p.enc = d_in[4];
  p.embeds = (const float*)d_in[5];
  p.Wq = d_in[6];
  p.vatt = (const float*)d_in[7];
  p.Wih1 = d_in[8];
  p.Whh1 = d_in[9];
  p.bih1 = (const float*)d_in[10];
  p.bhh1 = (const float*)d_in[11];
  p.Wih2 = d_in[12];
  p.Whh2 = d_in[13];
  p.bih2 = (const float*)d_in[14];
  p.bhh2 = (const float*)d_in[15];
  p.Wpre = d_in[16];
  p.bpre = (const float*)d_in[17];
  p.Wout = d_in[18];
  p.bout = (const float*)d_in[19];
  p.out = (float*)d_out;
  p.ws = (float*)d_ws;
  p.bar = (int*)d_ws;
  p.cw = (ws_size >= (size_t)(65536 + CONV_TOTAL * 2)) ? 1 : 0;

  void* args[] = {&p};
  hipError_t err = hipLaunchCooperativeKernel((const void*)dec_SAVE_30683246363209_kernel,
                                              dim3(GBLK), dim3(BT), args, 0, stream);
  if (err != hipSuccess) {
    // Fallback: plain launch. 256 blocks at 1 block/CU are trivially co-resident,
    // so the custom barrier remains safe.
    dec_SAVE_30683246363209_kernel<<<dim3(GBLK), dim3(BT), 0, stream>>>(p);
  }
}